// Round 5
// baseline (95.685 us; speedup 1.0000x reference)
//
#include <hip/hip_runtime.h>

// Problem constants (from reference setup_inputs)
#define B_  4
#define O_  32
#define C_  32
#define H_  32
#define W_  32
#define P_  5
#define T_  288      // C*3*3
#define EPSF 1e-6f

#define NCH 2                 // channels per block
#define CG  (C_ / NCH)        // 16 channel-groups

// Table layout per (o,t): 16 floats (float4-aligned quads)
//   q0 = inv_k  = 1/(p[k+1]-p[k]+EPS)      (k=0..3)
//   q1 = -p[k]*inv_k
//   q2 = v[k+1]-v[k]
//   q3.x = v[0]

__global__ __launch_bounds__(256) void zero_out(float* __restrict__ out, int n)
{
    int i = blockIdx.x * 256 + threadIdx.x;
    if (i < n) out[i] = 0.f;
}

__global__ __launch_bounds__(256) void prep_tables(
    const float* __restrict__ pos, const float* __restrict__ val,
    float* __restrict__ tab)
{
    int id = blockIdx.x * 256 + threadIdx.x;
    if (id >= O_ * T_) return;

    const float* pp = pos + id * P_;
    const float* vv = val + id * P_;
    float p0 = pp[0], p1 = pp[1], p2 = pp[2], p3 = pp[3], p4 = pp[4];
    float v0 = vv[0], v1 = vv[1], v2 = vv[2], v3 = vv[3], v4 = vv[4];

    // 9-CE sorting network for 5 elements, values carried along.
#define CSWAP(a, b, va, vb)                         \
    {                                               \
        float _pa = fminf(a, b), _pb = fmaxf(a, b); \
        bool _sw = (a > b);                         \
        float _va = _sw ? vb : va;                  \
        float _vb = _sw ? va : vb;                  \
        a = _pa; b = _pb; va = _va; vb = _vb;       \
    }
    CSWAP(p0, p1, v0, v1);
    CSWAP(p3, p4, v3, v4);
    CSWAP(p2, p4, v2, v4);
    CSWAP(p2, p3, v2, v3);
    CSWAP(p1, p4, v1, v4);
    CSWAP(p0, p3, v0, v3);
    CSWAP(p0, p2, v0, v2);
    CSWAP(p1, p3, v1, v3);
    CSWAP(p1, p2, v1, v2);
#undef CSWAP

    float inv0 = 1.0f / (p1 - p0 + EPSF);
    float inv1 = 1.0f / (p2 - p1 + EPSF);
    float inv2 = 1.0f / (p3 - p2 + EPSF);
    float inv3 = 1.0f / (p4 - p3 + EPSF);

    float* e = tab + id * 16;
    e[0]  = inv0;        e[1]  = inv1;        e[2]  = inv2;        e[3]  = inv3;
    e[4]  = -p0 * inv0;  e[5]  = -p1 * inv1;  e[6]  = -p2 * inv2;  e[7]  = -p3 * inv3;
    e[8]  = v1 - v0;     e[9]  = v2 - v1;     e[10] = v3 - v2;     e[11] = v4 - v3;
    e[12] = v0;          e[13] = 0.f;         e[14] = 0.f;         e[15] = 0.f;
}

// Block = (cg, o, b); 128 threads; full 32x32 image; 8 px/thread (2 rows x 4 cols).
// x slab: NCH channels, 34x34 halo, row stride 35 (bank pad).
#define XROW 34
#define XSTR 35
#define XS_PER_CH (XROW * XSTR)   // 1190

__global__ __launch_bounds__(128, 6) void pw_conv(
    const float* __restrict__ x, const float* __restrict__ tab,
    float* __restrict__ out)
{
    __shared__ float xs[NCH * XS_PER_CH];   // 9520 B

    const int cg = blockIdx.x;      // 0..CG-1
    const int o  = blockIdx.y;
    const int b  = blockIdx.z;
    const int tid = threadIdx.x;
    const int c0 = cg * NCH;

    // ---- stage x[b, c0..c0+1, -1..32, -1..32] into LDS (zero-padded) ----
    const float* xb = x + (b * C_ + c0) * (H_ * W_);
    for (int idx = tid; idx < NCH * XROW * XROW; idx += 128) {
        int ch  = idx / (XROW * XROW);
        int rem = idx - ch * (XROW * XROW);
        int r   = rem / XROW;             // 0..33 padded row
        int col = rem - r * XROW;         // 0..33 padded col
        int gr = r - 1, gc = col - 1;
        float v = 0.f;
        if ((unsigned)gr < (unsigned)H_ && (unsigned)gc < (unsigned)W_)
            v = xb[ch * (H_ * W_) + gr * W_ + gc];
        xs[ch * XS_PER_CH + r * XSTR + col] = v;
    }
    __syncthreads();

    const int r0 = (tid >> 3) * 2;    // 0,2,...,30  output row base
    const int c4 = (tid & 7) * 4;     // 0,4,...,28  output col base
    const float* tb = tab + (o * T_ + c0 * 9) * 16;

    float acc[2][4] = {{0.f, 0.f, 0.f, 0.f}, {0.f, 0.f, 0.f, 0.f}};

#pragma unroll
    for (int ch = 0; ch < NCH; ++ch) {
        // x window: padded rows r0..r0+3, padded cols c4..c4+5  (24 regs)
        float xw[4][6];
#pragma unroll
        for (int i = 0; i < 4; ++i)
#pragma unroll
            for (int j = 0; j < 6; ++j)
                xw[i][j] = xs[ch * XS_PER_CH + (r0 + i) * XSTR + c4 + j];

        const float4* e4 = (const float4*)(tb + ch * 9 * 16);
#pragma unroll
        for (int ij = 0; ij < 9; ++ij) {
            const int i = ij / 3, j = ij % 3;
            const float4 qi = e4[ij * 4 + 0];   // inv
            const float4 qf = e4[ij * 4 + 1];   // -p*inv
            const float4 qd = e4[ij * 4 + 2];   // dv
            const float4 qv = e4[ij * 4 + 3];   // v0 in .x

#pragma unroll
            for (int dr = 0; dr < 2; ++dr)
#pragma unroll
                for (int dc = 0; dc < 4; ++dc) {
                    float xv = xw[dr + i][dc + j];
                    float a  = acc[dr][dc] + qv.x;
                    float t;
                    t = fmaf(xv, qi.x, qf.x);
                    t = fminf(fmaxf(t, 0.f), 1.f); a = fmaf(t, qd.x, a);
                    t = fmaf(xv, qi.y, qf.y);
                    t = fminf(fmaxf(t, 0.f), 1.f); a = fmaf(t, qd.y, a);
                    t = fmaf(xv, qi.z, qf.z);
                    t = fminf(fmaxf(t, 0.f), 1.f); a = fmaf(t, qd.z, a);
                    t = fmaf(xv, qi.w, qf.w);
                    t = fminf(fmaxf(t, 0.f), 1.f); a = fmaf(t, qd.w, a);
                    acc[dr][dc] = a;
                }
        }
    }

    float* op = out + (b * O_ + o) * (H_ * W_);
#pragma unroll
    for (int dr = 0; dr < 2; ++dr)
#pragma unroll
        for (int dc = 0; dc < 4; ++dc)
            __hip_atomic_fetch_add(op + (r0 + dr) * W_ + c4 + dc, acc[dr][dc],
                                   __ATOMIC_RELAXED, __HIP_MEMORY_SCOPE_AGENT);
}

extern "C" void kernel_launch(void* const* d_in, const int* in_sizes, int n_in,
                              void* d_out, int out_size, void* d_ws, size_t ws_size,
                              hipStream_t stream)
{
    const float* x   = (const float*)d_in[0];
    const float* pos = (const float*)d_in[1];
    const float* val = (const float*)d_in[2];
    float* tab = (float*)d_ws;              // needs 32*288*16*4 = 589824 B

    // Output accumulated via atomics -> zero it first (d_out is poisoned 0xAA).
    zero_out<<<(out_size + 255) / 256, 256, 0, stream>>>((float*)d_out, out_size);

    // Phase 1: sort breakpoints + precompute segment coefficients.
    prep_tables<<<(O_ * T_ + 255) / 256, 256, 0, stream>>>(pos, val, tab);

    // Phase 2: evaluate. grid = (channel groups, O, B)
    dim3 grid(CG, O_, B_);
    pw_conv<<<grid, 128, 0, stream>>>(x, tab, (float*)d_out);
}

// Round 6
// 94.060 us; speedup vs baseline: 1.0173x; 1.0173x over previous
//
#include <hip/hip_runtime.h>

// Problem constants (from reference setup_inputs)
#define B_  4
#define O_  32
#define C_  32
#define H_  32
#define W_  32
#define P_  5
#define T_  288      // C*3*3
#define EPSF 1e-6f

#define NCH 2                 // channels per block (LDS = 9520B -> not LDS-capped)
#define CG  (C_ / NCH)        // 16 channel-groups

// Table layout per (o,t): 16 floats (float4-aligned quads)
//   q0 = inv_k  = 1/(p[k+1]-p[k]+EPS)      (k=0..3)
//   q1 = -p[k]*inv_k
//   q2 = v[k+1]-v[k]
//   q3.x = v[0]

__global__ __launch_bounds__(256) void zero_out(float* __restrict__ out, int n)
{
    int i = blockIdx.x * 256 + threadIdx.x;
    if (i < n) out[i] = 0.f;
}

__global__ __launch_bounds__(256) void prep_tables(
    const float* __restrict__ pos, const float* __restrict__ val,
    float* __restrict__ tab)
{
    int id = blockIdx.x * 256 + threadIdx.x;
    if (id >= O_ * T_) return;

    const float* pp = pos + id * P_;
    const float* vv = val + id * P_;
    float p0 = pp[0], p1 = pp[1], p2 = pp[2], p3 = pp[3], p4 = pp[4];
    float v0 = vv[0], v1 = vv[1], v2 = vv[2], v3 = vv[3], v4 = vv[4];

    // 9-CE sorting network for 5 elements, values carried along.
#define CSWAP(a, b, va, vb)                         \
    {                                               \
        float _pa = fminf(a, b), _pb = fmaxf(a, b); \
        bool _sw = (a > b);                         \
        float _va = _sw ? vb : va;                  \
        float _vb = _sw ? va : vb;                  \
        a = _pa; b = _pb; va = _va; vb = _vb;       \
    }
    CSWAP(p0, p1, v0, v1);
    CSWAP(p3, p4, v3, v4);
    CSWAP(p2, p4, v2, v4);
    CSWAP(p2, p3, v2, v3);
    CSWAP(p1, p4, v1, v4);
    CSWAP(p0, p3, v0, v3);
    CSWAP(p0, p2, v0, v2);
    CSWAP(p1, p3, v1, v3);
    CSWAP(p1, p2, v1, v2);
#undef CSWAP

    float inv0 = 1.0f / (p1 - p0 + EPSF);
    float inv1 = 1.0f / (p2 - p1 + EPSF);
    float inv2 = 1.0f / (p3 - p2 + EPSF);
    float inv3 = 1.0f / (p4 - p3 + EPSF);

    float* e = tab + id * 16;
    e[0]  = inv0;        e[1]  = inv1;        e[2]  = inv2;        e[3]  = inv3;
    e[4]  = -p0 * inv0;  e[5]  = -p1 * inv1;  e[6]  = -p2 * inv2;  e[7]  = -p3 * inv3;
    e[8]  = v1 - v0;     e[9]  = v2 - v1;     e[10] = v3 - v2;     e[11] = v4 - v3;
    e[12] = v0;          e[13] = 0.f;         e[14] = 0.f;         e[15] = 0.f;
}

// Block = (cg, o, b); 256 threads; full 32x32 image; 4 px/thread (1 row x 4 cols).
// x slab: NCH channels, 34x34 halo, row stride 35 (bank pad).
#define XROW 34
#define XSTR 35
#define XS_PER_CH (XROW * XSTR)   // 1190

__global__ __launch_bounds__(256, 4) void pw_conv(
    const float* __restrict__ x, const float* __restrict__ tab,
    float* __restrict__ out)
{
    __shared__ float xs[NCH * XS_PER_CH];   // 9520 B

    const int cg = blockIdx.x;      // 0..CG-1
    const int o  = blockIdx.y;
    const int b  = blockIdx.z;
    const int tid = threadIdx.x;
    const int c0 = cg * NCH;

    // ---- stage x[b, c0..c0+NCH-1, -1..32, -1..32] into LDS (zero-padded) ----
    const float* xb = x + (b * C_ + c0) * (H_ * W_);
    for (int idx = tid; idx < NCH * XROW * XROW; idx += 256) {
        int ch  = idx / (XROW * XROW);
        int rem = idx - ch * (XROW * XROW);
        int r   = rem / XROW;             // 0..33 padded row
        int col = rem - r * XROW;         // 0..33 padded col
        int gr = r - 1, gc = col - 1;
        float v = 0.f;
        if ((unsigned)gr < (unsigned)H_ && (unsigned)gc < (unsigned)W_)
            v = xb[ch * (H_ * W_) + gr * W_ + gc];
        xs[ch * XS_PER_CH + r * XSTR + col] = v;
    }
    __syncthreads();

    const int r  = tid >> 3;          // 0..31 output row
    const int c4 = (tid & 7) * 4;     // 0,4,...,28 output col base
    const float* tb = tab + (o * T_ + c0 * 9) * 16;

    float acc0 = 0.f, acc1 = 0.f, acc2 = 0.f, acc3 = 0.f;

#pragma unroll
    for (int ch = 0; ch < NCH; ++ch) {
        // x window: padded rows r..r+2, padded cols c4..c4+5  (18 regs)
        float xr[3][6];
#pragma unroll
        for (int i = 0; i < 3; ++i)
#pragma unroll
            for (int j = 0; j < 6; ++j)
                xr[i][j] = xs[ch * XS_PER_CH + (r + i) * XSTR + c4 + j];

        const float* ec = tb + ch * 9 * 16;
#pragma unroll
        for (int ij = 0; ij < 9; ++ij) {
            const int i = ij / 3, j = ij % 3;
            const float* e = ec + ij * 16;
            float i0 = e[0], i1 = e[1], i2 = e[2], i3 = e[3];
            float f0 = e[4], f1 = e[5], f2 = e[6], f3 = e[7];
            float d0 = e[8], d1 = e[9], d2 = e[10], d3 = e[11];
            float v0 = e[12];

#define EVAL(ACC, XV)                                                      \
            {                                                              \
                float _xv = (XV);                                          \
                ACC += v0;                                                 \
                float _t;                                                  \
                _t = fmaf(_xv, i0, f0);                                    \
                _t = fminf(fmaxf(_t, 0.f), 1.f); ACC = fmaf(_t, d0, ACC);  \
                _t = fmaf(_xv, i1, f1);                                    \
                _t = fminf(fmaxf(_t, 0.f), 1.f); ACC = fmaf(_t, d1, ACC);  \
                _t = fmaf(_xv, i2, f2);                                    \
                _t = fminf(fmaxf(_t, 0.f), 1.f); ACC = fmaf(_t, d2, ACC);  \
                _t = fmaf(_xv, i3, f3);                                    \
                _t = fminf(fmaxf(_t, 0.f), 1.f); ACC = fmaf(_t, d3, ACC);  \
            }
            EVAL(acc0, xr[i][j + 0]);
            EVAL(acc1, xr[i][j + 1]);
            EVAL(acc2, xr[i][j + 2]);
            EVAL(acc3, xr[i][j + 3]);
#undef EVAL
        }
    }

    float* op = out + (b * O_ + o) * (H_ * W_) + r * W_ + c4;
    __hip_atomic_fetch_add(op + 0, acc0, __ATOMIC_RELAXED, __HIP_MEMORY_SCOPE_AGENT);
    __hip_atomic_fetch_add(op + 1, acc1, __ATOMIC_RELAXED, __HIP_MEMORY_SCOPE_AGENT);
    __hip_atomic_fetch_add(op + 2, acc2, __ATOMIC_RELAXED, __HIP_MEMORY_SCOPE_AGENT);
    __hip_atomic_fetch_add(op + 3, acc3, __ATOMIC_RELAXED, __HIP_MEMORY_SCOPE_AGENT);
}

extern "C" void kernel_launch(void* const* d_in, const int* in_sizes, int n_in,
                              void* d_out, int out_size, void* d_ws, size_t ws_size,
                              hipStream_t stream)
{
    const float* x   = (const float*)d_in[0];
    const float* pos = (const float*)d_in[1];
    const float* val = (const float*)d_in[2];
    float* tab = (float*)d_ws;              // needs 32*288*16*4 = 589824 B

    // Output accumulated via atomics -> zero it first (d_out is poisoned 0xAA).
    zero_out<<<(out_size + 255) / 256, 256, 0, stream>>>((float*)d_out, out_size);

    // Phase 1: sort breakpoints + precompute segment coefficients.
    prep_tables<<<(O_ * T_ + 255) / 256, 256, 0, stream>>>(pos, val, tab);

    // Phase 2: evaluate. grid = (channel groups, O, B)
    dim3 grid(CG, O_, B_);
    pw_conv<<<grid, 256, 0, stream>>>(x, tab, (float*)d_out);
}

// Round 9
// 77.016 us; speedup vs baseline: 1.2424x; 1.2213x over previous
//
#include <hip/hip_runtime.h>

// Problem constants (from reference setup_inputs)
#define B_  4
#define O_  32
#define C_  32
#define H_  32
#define W_  32
#define P_  5
#define T_  288      // C*3*3
#define PIX (H_ * W_)  // 1024
#define EPSF 1e-6f

#define NCH 2                 // channels per block
#define CG  (C_ / NCH)        // 16 channel-groups

// Table layout per (o,t): 16 floats (float4 quads)
//   q0 = inv_k  = 1/(p[k+1]-p[k]+EPS)   (k=0..3)
//   q1 = -p[k]*inv_k
//   q2 = v[k+1]-v[k]
//   q3.x = v[0]

__global__ __launch_bounds__(256) void prep_tables(
    const float* __restrict__ pos, const float* __restrict__ val,
    float* __restrict__ tab)
{
    int id = blockIdx.x * 256 + threadIdx.x;
    if (id >= O_ * T_) return;

    const float* pp = pos + id * P_;
    const float* vv = val + id * P_;
    float p0 = pp[0], p1 = pp[1], p2 = pp[2], p3 = pp[3], p4 = pp[4];
    float v0 = vv[0], v1 = vv[1], v2 = vv[2], v3 = vv[3], v4 = vv[4];

    // 9-CE sorting network for 5 elements, values carried along.
#define CSWAP(a, b, va, vb)                         \
    {                                               \
        float _pa = fminf(a, b), _pb = fmaxf(a, b); \
        bool _sw = (a > b);                         \
        float _va = _sw ? vb : va;                  \
        float _vb = _sw ? va : vb;                  \
        a = _pa; b = _pb; va = _va; vb = _vb;       \
    }
    CSWAP(p0, p1, v0, v1);
    CSWAP(p3, p4, v3, v4);
    CSWAP(p2, p4, v2, v4);
    CSWAP(p2, p3, v2, v3);
    CSWAP(p1, p4, v1, v4);
    CSWAP(p0, p3, v0, v3);
    CSWAP(p0, p2, v0, v2);
    CSWAP(p1, p3, v1, v3);
    CSWAP(p1, p2, v1, v2);
#undef CSWAP

    float inv0 = 1.0f / (p1 - p0 + EPSF);
    float inv1 = 1.0f / (p2 - p1 + EPSF);
    float inv2 = 1.0f / (p3 - p2 + EPSF);
    float inv3 = 1.0f / (p4 - p3 + EPSF);

    float* e = tab + id * 16;
    e[0]  = inv0;        e[1]  = inv1;        e[2]  = inv2;        e[3]  = inv3;
    e[4]  = -p0 * inv0;  e[5]  = -p1 * inv1;  e[6]  = -p2 * inv2;  e[7]  = -p3 * inv3;
    e[8]  = v1 - v0;     e[9]  = v2 - v1;     e[10] = v3 - v2;     e[11] = v4 - v3;
    e[12] = v0;          e[13] = 0.f;         e[14] = 0.f;         e[15] = 0.f;
}

// Block = (cg, o, b); 256 threads; full 32x32 image; 4 px/thread (1 row x 4 cols).
// x slab: NCH channels, 34x34 halo, row stride 35 (bank pad). Tables in LDS.
#define XROW 34
#define XSTR 35
#define XS_PER_CH (XROW * XSTR)   // 1190
#define TABF (NCH * 9 * 16)       // 288 floats

__global__ __launch_bounds__(256, 4) void pw_conv(
    const float* __restrict__ x, const float* __restrict__ tab,
    float* __restrict__ part)
{
    __shared__ float xs[NCH * XS_PER_CH];   // 9520 B
    __shared__ float ts[TABF];              // 1152 B

    const int cg = blockIdx.x;      // 0..CG-1
    const int o  = blockIdx.y;
    const int b  = blockIdx.z;
    const int tid = threadIdx.x;
    const int c0 = cg * NCH;

    // ---- stage this block's table slice into LDS (288 floats) ----
    const float* tg = tab + (o * T_ + c0 * 9) * 16;
    for (int i = tid; i < TABF; i += 256) ts[i] = tg[i];

    // ---- stage x[b, c0..c0+NCH-1, -1..32, -1..32] into LDS (zero-padded) ----
    const float* xb = x + (b * C_ + c0) * PIX;
    for (int idx = tid; idx < NCH * XROW * XROW; idx += 256) {
        int ch  = idx / (XROW * XROW);
        int rem = idx - ch * (XROW * XROW);
        int r   = rem / XROW;             // 0..33 padded row
        int col = rem - r * XROW;         // 0..33 padded col
        int gr = r - 1, gc = col - 1;
        float v = 0.f;
        if ((unsigned)gr < (unsigned)H_ && (unsigned)gc < (unsigned)W_)
            v = xb[ch * PIX + gr * W_ + gc];
        xs[ch * XS_PER_CH + r * XSTR + col] = v;
    }
    __syncthreads();

    const int r  = tid >> 3;          // 0..31 output row
    const int c4 = (tid & 7) * 4;     // 0,4,...,28 output col base

    float acc0 = 0.f, acc1 = 0.f, acc2 = 0.f, acc3 = 0.f;

#pragma unroll
    for (int ch = 0; ch < NCH; ++ch) {
        // x window: padded rows r..r+2, padded cols c4..c4+5 (18 regs)
        float xr[3][6];
#pragma unroll
        for (int i = 0; i < 3; ++i)
#pragma unroll
            for (int j = 0; j < 6; ++j)
                xr[i][j] = xs[ch * XS_PER_CH + (r + i) * XSTR + c4 + j];

        const float4* e4 = (const float4*)(ts + ch * 9 * 16);
#pragma unroll
        for (int ij = 0; ij < 9; ++ij) {
            const int i = ij / 3, j = ij % 3;
            // uniform-address ds_read_b128 -> LDS broadcast (conflict-free)
            const float4 qi = e4[ij * 4 + 0];   // inv
            const float4 qf = e4[ij * 4 + 1];   // -p*inv
            const float4 qd = e4[ij * 4 + 2];   // dv
            const float  v0 = e4[ij * 4 + 3].x; // v0

#define EVAL(ACC, XV)                                                        \
            {                                                                \
                float _xv = (XV);                                            \
                ACC += v0;                                                   \
                float _t;                                                    \
                _t = fmaf(_xv, qi.x, qf.x);                                  \
                _t = fminf(fmaxf(_t, 0.f), 1.f); ACC = fmaf(_t, qd.x, ACC);  \
                _t = fmaf(_xv, qi.y, qf.y);                                  \
                _t = fminf(fmaxf(_t, 0.f), 1.f); ACC = fmaf(_t, qd.y, ACC);  \
                _t = fmaf(_xv, qi.z, qf.z);                                  \
                _t = fminf(fmaxf(_t, 0.f), 1.f); ACC = fmaf(_t, qd.z, ACC);  \
                _t = fmaf(_xv, qi.w, qf.w);                                  \
                _t = fminf(fmaxf(_t, 0.f), 1.f); ACC = fmaf(_t, qd.w, ACC);  \
            }
            EVAL(acc0, xr[i][j + 0]);
            EVAL(acc1, xr[i][j + 1]);
            EVAL(acc2, xr[i][j + 2]);
            EVAL(acc3, xr[i][j + 3]);
#undef EVAL
        }
    }

    // coalesced partial write: addr = 4*tid matches (r*W_ + c4)
    float4 res; res.x = acc0; res.y = acc1; res.z = acc2; res.w = acc3;
    float4* pp = (float4*)(part + ((size_t)(cg * B_ + b) * O_ + o) * PIX);
    pp[tid] = res;
}

// Sum the CG partial images: out[j] = sum_cg part[cg][j], float4-vectorized.
__global__ __launch_bounds__(256) void reduce16(
    const float* __restrict__ part, float* __restrict__ out)
{
    int j = blockIdx.x * 256 + threadIdx.x;        // float4 index, 32768 total
    const float4* p4 = (const float4*)part;
    float4 s; s.x = 0.f; s.y = 0.f; s.z = 0.f; s.w = 0.f;
#pragma unroll
    for (int cg = 0; cg < CG; ++cg) {
        float4 p = p4[cg * (B_ * O_ * PIX / 4) + j];
        s.x += p.x; s.y += p.y; s.z += p.z; s.w += p.w;
    }
    ((float4*)out)[j] = s;
}

extern "C" void kernel_launch(void* const* d_in, const int* in_sizes, int n_in,
                              void* d_out, int out_size, void* d_ws, size_t ws_size,
                              hipStream_t stream)
{
    const float* x   = (const float*)d_in[0];
    const float* pos = (const float*)d_in[1];
    const float* val = (const float*)d_in[2];

    float* tab  = (float*)d_ws;                      // 589824 B
    float* part = (float*)((char*)d_ws + (1 << 20)); // CG*B*O*PIX floats = 8 MB

    // Phase 1: sort breakpoints + precompute segment coefficients.
    prep_tables<<<(O_ * T_ + 255) / 256, 256, 0, stream>>>(pos, val, tab);

    // Phase 2: evaluate into per-channel-group partials. grid = (CG, O, B)
    dim3 grid(CG, O_, B_);
    pw_conv<<<grid, 256, 0, stream>>>(x, tab, part);

    // Phase 3: reduce partials into d_out (overwrites poison; no zeroing needed).
    int n4 = B_ * O_ * PIX / 4;                      // 32768
    reduce16<<<n4 / 256, 256, 0, stream>>>(part, (float*)d_out);
}

// Round 10
// 75.018 us; speedup vs baseline: 1.2755x; 1.0266x over previous
//
#include <hip/hip_runtime.h>

// Problem constants (from reference setup_inputs)
#define B_  4
#define O_  32
#define C_  32
#define H_  32
#define W_  32
#define P_  5
#define T_  288        // C*3*3
#define PIX (H_ * W_)  // 1024
#define EPSF 1e-6f

#define NCH 2                 // input channels per block
#define CG  (C_ / NCH)        // 16 channel-groups
#define NO  2                 // output channels per block
#define OG  (O_ / NO)         // 16 o-groups

// Per-entry table layout (16 floats, float4 quads):
//   q0 = inv_k = 1/(p[k+1]-p[k]+EPS) (k=0..3); q1 = -p[k]*inv_k;
//   q2 = v[k+1]-v[k]; q3.x = v[0]
#define ENT (NO * NCH * 9)        // 36 entries per block
#define TABF (ENT * 16)           // 576 floats

// x slab: NCH channels, 34x34 halo, row stride 35 (bank pad).
#define XROW 34
#define XSTR 35
#define XS_PER_CH (XROW * XSTR)   // 1190

__global__ __launch_bounds__(256, 4) void pw_conv(
    const float* __restrict__ x, const float* __restrict__ pos,
    const float* __restrict__ val, float* __restrict__ part)
{
    __shared__ float xs[NCH * XS_PER_CH];   // 9520 B
    __shared__ float ts[TABF];              // 2304 B

    const int cg = blockIdx.x;      // 0..CG-1
    const int og = blockIdx.y;      // 0..OG-1
    const int b  = blockIdx.z;
    const int tid = threadIdx.x;
    const int c0 = cg * NCH;
    const int o0 = og * NO;

    // ---- fused table prep: threads 0..35 sort one (o,t) entry each ----
    if (tid < ENT) {
        const int oo = tid / (NCH * 9);
        const int rem = tid - oo * (NCH * 9);     // 0..17
        const int id = (o0 + oo) * T_ + c0 * 9 + rem;   // global (o,t) entry

        const float* pp = pos + id * P_;
        const float* vv = val + id * P_;
        float p0 = pp[0], p1 = pp[1], p2 = pp[2], p3 = pp[3], p4 = pp[4];
        float v0 = vv[0], v1 = vv[1], v2 = vv[2], v3 = vv[3], v4 = vv[4];

        // 9-CE sorting network for 5 elements, values carried along.
#define CSWAP(a, bb, va, vb)                        \
        {                                           \
            float _pa = fminf(a, bb), _pb = fmaxf(a, bb); \
            bool _sw = (a > bb);                    \
            float _va = _sw ? vb : va;              \
            float _vb = _sw ? va : vb;              \
            a = _pa; bb = _pb; va = _va; vb = _vb;  \
        }
        CSWAP(p0, p1, v0, v1);
        CSWAP(p3, p4, v3, v4);
        CSWAP(p2, p4, v2, v4);
        CSWAP(p2, p3, v2, v3);
        CSWAP(p1, p4, v1, v4);
        CSWAP(p0, p3, v0, v3);
        CSWAP(p0, p2, v0, v2);
        CSWAP(p1, p3, v1, v3);
        CSWAP(p1, p2, v1, v2);
#undef CSWAP

        float inv0 = 1.0f / (p1 - p0 + EPSF);
        float inv1 = 1.0f / (p2 - p1 + EPSF);
        float inv2 = 1.0f / (p3 - p2 + EPSF);
        float inv3 = 1.0f / (p4 - p3 + EPSF);

        float* e = ts + tid * 16;
        e[0]  = inv0;        e[1]  = inv1;        e[2]  = inv2;        e[3]  = inv3;
        e[4]  = -p0 * inv0;  e[5]  = -p1 * inv1;  e[6]  = -p2 * inv2;  e[7]  = -p3 * inv3;
        e[8]  = v1 - v0;     e[9]  = v2 - v1;     e[10] = v3 - v2;     e[11] = v4 - v3;
        e[12] = v0;          e[13] = 0.f;         e[14] = 0.f;         e[15] = 0.f;
    }

    // ---- stage x[b, c0..c0+NCH-1, -1..32, -1..32] into LDS (zero-padded) ----
    const float* xb = x + (b * C_ + c0) * PIX;
    for (int idx = tid; idx < NCH * XROW * XROW; idx += 256) {
        int ch  = idx / (XROW * XROW);
        int rem = idx - ch * (XROW * XROW);
        int r   = rem / XROW;             // 0..33 padded row
        int col = rem - r * XROW;         // 0..33 padded col
        int gr = r - 1, gc = col - 1;
        float v = 0.f;
        if ((unsigned)gr < (unsigned)H_ && (unsigned)gc < (unsigned)W_)
            v = xb[ch * PIX + gr * W_ + gc];
        xs[ch * XS_PER_CH + r * XSTR + col] = v;
    }
    __syncthreads();

    const int r  = tid >> 3;          // 0..31 output row
    const int c4 = (tid & 7) * 4;     // 0,4,...,28 output col base

    float acc[NO][4] = {{0.f, 0.f, 0.f, 0.f}, {0.f, 0.f, 0.f, 0.f}};

#pragma unroll
    for (int ch = 0; ch < NCH; ++ch) {
        // x window: padded rows r..r+2, padded cols c4..c4+5 (18 regs)
        float xr[3][6];
#pragma unroll
        for (int i = 0; i < 3; ++i)
#pragma unroll
            for (int j = 0; j < 6; ++j)
                xr[i][j] = xs[ch * XS_PER_CH + (r + i) * XSTR + c4 + j];

#pragma unroll
        for (int oo = 0; oo < NO; ++oo) {
            const float4* e4 = (const float4*)(ts + (oo * NCH + ch) * 9 * 16);
#pragma unroll
            for (int ij = 0; ij < 9; ++ij) {
                const int i = ij / 3, j = ij % 3;
                // uniform-address ds_read_b128 -> LDS broadcast (conflict-free)
                const float4 qi = e4[ij * 4 + 0];   // inv
                const float4 qf = e4[ij * 4 + 1];   // -p*inv
                const float4 qd = e4[ij * 4 + 2];   // dv
                const float  v0 = e4[ij * 4 + 3].x; // v0

#define EVAL(ACC, XV)                                                        \
                {                                                            \
                    float _xv = (XV);                                        \
                    ACC += v0;                                               \
                    float _t;                                                \
                    _t = fmaf(_xv, qi.x, qf.x);                              \
                    _t = fminf(fmaxf(_t, 0.f), 1.f); ACC = fmaf(_t, qd.x, ACC); \
                    _t = fmaf(_xv, qi.y, qf.y);                              \
                    _t = fminf(fmaxf(_t, 0.f), 1.f); ACC = fmaf(_t, qd.y, ACC); \
                    _t = fmaf(_xv, qi.z, qf.z);                              \
                    _t = fminf(fmaxf(_t, 0.f), 1.f); ACC = fmaf(_t, qd.z, ACC); \
                    _t = fmaf(_xv, qi.w, qf.w);                              \
                    _t = fminf(fmaxf(_t, 0.f), 1.f); ACC = fmaf(_t, qd.w, ACC); \
                }
                EVAL(acc[oo][0], xr[i][j + 0]);
                EVAL(acc[oo][1], xr[i][j + 1]);
                EVAL(acc[oo][2], xr[i][j + 2]);
                EVAL(acc[oo][3], xr[i][j + 3]);
#undef EVAL
            }
        }
    }

    // coalesced partial writes: addr = 4*tid matches (r*W_ + c4)
#pragma unroll
    for (int oo = 0; oo < NO; ++oo) {
        float4 res;
        res.x = acc[oo][0]; res.y = acc[oo][1];
        res.z = acc[oo][2]; res.w = acc[oo][3];
        float4* pp = (float4*)(part + ((size_t)(cg * B_ + b) * O_ + o0 + oo) * PIX);
        pp[tid] = res;
    }
}

// Sum the CG partial images: out[j] = sum_cg part[cg][j], float4-vectorized.
__global__ __launch_bounds__(256) void reduce16(
    const float* __restrict__ part, float* __restrict__ out)
{
    int j = blockIdx.x * 256 + threadIdx.x;        // float4 index, 32768 total
    const float4* p4 = (const float4*)part;
    float4 s; s.x = 0.f; s.y = 0.f; s.z = 0.f; s.w = 0.f;
#pragma unroll
    for (int cg = 0; cg < CG; ++cg) {
        float4 p = p4[cg * (B_ * O_ * PIX / 4) + j];
        s.x += p.x; s.y += p.y; s.z += p.z; s.w += p.w;
    }
    ((float4*)out)[j] = s;
}

extern "C" void kernel_launch(void* const* d_in, const int* in_sizes, int n_in,
                              void* d_out, int out_size, void* d_ws, size_t ws_size,
                              hipStream_t stream)
{
    const float* x   = (const float*)d_in[0];
    const float* pos = (const float*)d_in[1];
    const float* val = (const float*)d_in[2];

    float* part = (float*)d_ws;     // CG*B*O*PIX floats = 8 MB

    // Phase 1: fused table-prep + evaluate into per-channel-group partials.
    dim3 grid(CG, OG, B_);
    pw_conv<<<grid, 256, 0, stream>>>(x, pos, val, part);

    // Phase 2: reduce partials into d_out (overwrites poison; no zeroing needed).
    int n4 = B_ * O_ * PIX / 4;     // 32768
    reduce16<<<n4 / 256, 256, 0, stream>>>(part, (float*)d_out);
}